// Round 14
// baseline (436.287 us; speedup 1.0000x reference)
//
#include <hip/hip_runtime.h>

#define HD 64
#define VOCAB 64
#define BATCH 256
#define SEQLEN 2048
#define NSTEPS ((SEQLEN - 2) / 2)   // 1023
#define LRc 0.05f

typedef __attribute__((ext_vector_type(2))) float f2;

// Cross-half (lane l <-> l^32) sum via v_permlane32_swap_b32 (VALU-class).
// r0[l] = x[l&31] (lo half), r1[l] = x[(l&31)+32] (hi half) -> r0+r1 is the
// cross-half sum in every lane; bit-identical to x + shfl_xor(x,32).
__device__ __forceinline__ float xsum32(float x) {
  unsigned int u = __float_as_uint(x);
  auto r = __builtin_amdgcn_permlane32_swap(u, u, false, false);
  return __uint_as_float(r[0]) + __uint_as_float(r[1]);
}

// acc += w * shp  where shp is a wave-uniform f2 held in an SGPR pair.
// VOP3P v_pk_fma_f32 with the single allowed scalar operand in src0.
__device__ __forceinline__ void pk_fma_s(f2& acc, const f2& w, const f2& shp) {
  asm("v_pk_fma_f32 %0, %2, %1, %0" : "+v"(acc) : "v"(w), "s"(shp));
}

// ---------------- Kernel 1: build the 64x64 encoder table ----------------
__global__ __launch_bounds__(64, 1) void enc_build(
    const float* __restrict__ embed, const float* __restrict__ ffw1,
    const float* __restrict__ ffb1, const float* __restrict__ ffw2,
    const float* __restrict__ ffb2, const float* __restrict__ ln_g,
    const float* __restrict__ ln_b, float* __restrict__ enc) {
  const int v = blockIdx.x, j = threadIdx.x;
  __shared__ float e_s[HD];
  __shared__ float hid_s[2 * HD];
  float e = embed[v * HD + j];
  e_s[j] = e;
  __syncthreads();
  float ha = ffb1[j], hb = ffb1[HD + j];
  #pragma unroll 8
  for (int h = 0; h < HD; ++h) {
    float eh = e_s[h];
    ha = fmaf(ffw1[j * HD + h], eh, ha);
    hb = fmaf(ffw1[(HD + j) * HD + h], eh, hb);
  }
  hid_s[j] = fmaxf(ha, 0.f);
  hid_s[HD + j] = fmaxf(hb, 0.f);
  __syncthreads();
  float ff = ffb2[j];
  #pragma unroll 8
  for (int h2 = 0; h2 < 2 * HD; ++h2) ff = fmaf(ffw2[j * 2 * HD + h2], hid_s[h2], ff);
  float x = e + ff;
  float mu = x;
  #pragma unroll
  for (int m = 1; m < 64; m <<= 1) mu += __shfl_xor(mu, m, 64);
  mu *= (1.f / 64.f);
  float xc = x - mu;
  float var = xc * xc;
  #pragma unroll
  for (int m = 1; m < 64; m <<= 1) var += __shfl_xor(var, m, 64);
  var *= (1.f / 64.f);
  enc[v * HD + j] = xc / sqrtf(var + 1e-5f) * ln_g[j] + ln_b[j];
}

// ---------------- Kernel 1b: Gram matrix G[u][v] = enc_u . enc_v ----------------
__global__ __launch_bounds__(64, 1) void gram_build(
    const float* __restrict__ enc, float* __restrict__ G) {
  __shared__ float es[VOCAB * HD];
  const int u = blockIdx.x, v = threadIdx.x;
  #pragma unroll
  for (int q = 0; q < 16; ++q)
    ((float4*)es)[v + 64 * q] = ((const float4*)enc)[v + 64 * q];
  __syncthreads();
  const float* a = &es[u * HD];
  const float* bb = &es[v * HD];
  float s0 = 0.f, s1 = 0.f, s2 = 0.f, s3 = 0.f;
  #pragma unroll
  for (int j = 0; j < HD; j += 4) {
    s0 = fmaf(a[j + 0], bb[j + 0], s0);
    s1 = fmaf(a[j + 1], bb[j + 1], s1);
    s2 = fmaf(a[j + 2], bb[j + 2], s2);
    s3 = fmaf(a[j + 3], bb[j + 3], s3);
  }
  G[u * VOCAB + v] = (s0 + s1) + (s2 + s3);
}

// ---------------- Kernel 2: the sequential TTT scan ----------------
// One wave per chain, state in VGPRs. lane l = 32*half + i:
//   W1[c]   = w1[i][32*half + 2c..2c+1]   (f2)
//   W2R2[c] = w2[l][2c..2c+1]             (f2; pk ops with SGPR-pair sh)
//   W2T[r]  = w2[32*half + 2r..2r+1][i]   (f2)
// Carry: pre_{t+1} = POFb + dh_t * G[tok_t][tok_{t+1}],  POFb = W1_t@k_{t+1} + b1.
__device__ __forceinline__ void ttt_step(
    int l, int half,
    const float* __restrict__ enc_s, const float* __restrict__ G_s,
    const int* __restrict__ seq_s, float* __restrict__ sd_s,
    f2 (&W1)[16], f2 (&W2R2)[16], f2 (&W2T)[16],
    float& b1r, float& b2r,
    f2 (&KC)[16], float& vvC, f2 (&KN)[16], float& vvN,
    float& POFb, float& KKF, float& dhp,
    int2& tk, int2& tk1, int pidx) {
  // ---- pre from carried rank-1 correction (critical: fma+max) ----
  float pre = fmaf(dhp, KKF, POFb);
  float h = fmaxf(pre, 0.f);

  // ---- issue next tokens' K/vv/Gram/seq loads (consumed much later) ----
  const float* krn = &enc_s[tk1.x * HD + half * 32];
  float4* kn4 = (float4*)&KN[0];
  #pragma unroll
  for (int q = 0; q < 8; ++q) kn4[q] = *(const float4*)&krn[4 * q];
  vvN = enc_s[tk1.y * HD + l];
  float KKFn = G_s[tk.x * VOCAB + tk1.x];
  int2 tk2 = *(const int2*)&seq_s[pidx];

  // ---- broadcast h[0..31] via v_readlane into SGPR PAIRS ----
  f2 shp[16];
  #pragma unroll
  for (int c = 0; c < 16; ++c) {
    float a = __int_as_float(__builtin_amdgcn_readlane(__float_as_int(h), 2 * c));
    float bq = __int_as_float(__builtin_amdgcn_readlane(__float_as_int(h), 2 * c + 1));
    shp[c] = f2{a, bq};
  }

  // ---- pred[l] = w2[l,:] @ h + b2[l]  (16 pk_fma with SGPR-pair operand) ----
  f2 qa = {b2r, 0.f}, qb = {0.f, 0.f}, qc = {0.f, 0.f}, qd = {0.f, 0.f};
  #pragma unroll
  for (int c = 0; c < 16; c += 4) {
    pk_fma_s(qa, W2R2[c + 0], shp[c + 0]);
    pk_fma_s(qb, W2R2[c + 1], shp[c + 1]);
    pk_fma_s(qc, W2R2[c + 2], shp[c + 2]);
    pk_fma_s(qd, W2R2[c + 3], shp[c + 3]);
  }
  float pred = ((qa.x + qa.y) + (qb.x + qb.y)) + ((qc.x + qc.y) + (qd.x + qd.y));
  float sR = (vvC - pred) * (2.f * LRc / (float)HD);
  sd_s[l] = sR;  // scaled-d broadcast

  // ---- SD reads issue here; consumed after the fill below ----
  f2 SD[16];
  {
    const float* drp = &sd_s[half * 32];
    float4* sd4 = (float4*)&SD[0];
    #pragma unroll
    for (int q = 0; q < 8; ++q) sd4[q] = *(const float4*)&drp[4 * q];
  }

  // ======== fill (SD-independent): W2R update (pk) + POF dot ========
  f2 sr2 = {sR, sR};
  #pragma unroll
  for (int c = 0; c < 16; ++c) pk_fma_s(W2R2[c], sr2, shp[c]);
  b2r += sR;
  f2 p0 = {0.f, 0.f}, p1 = {0.f, 0.f};
  #pragma unroll
  for (int c = 0; c < 16; c += 2) {
    p0 = __builtin_elementwise_fma(W1[c + 0], KN[c + 0], p0);
    p1 = __builtin_elementwise_fma(W1[c + 1], KN[c + 1], p1);
  }
  f2 ps = p0 + p1;
  float POFn = xsum32(ps.x + ps.y);
  float PB = POFn + b1r;   // b1r still pre-update
  // ==================================================================

  // ---- dh' = -LR * (w2^T @ d)[i], masked by relu ----
  f2 g0 = {0.f, 0.f}, g1 = {0.f, 0.f};
  #pragma unroll
  for (int r = 0; r < 16; r += 2) {
    g0 = __builtin_elementwise_fma(W2T[r + 0], SD[r + 0], g0);
    g1 = __builtin_elementwise_fma(W2T[r + 1], SD[r + 1], g1);
  }
  f2 gs = g0 + g1;
  float dh = xsum32(gs.x + gs.y);
  dh = (pre > 0.f) ? dh : 0.f;

  // ---- updates (per-element fma; W2R/W2T stay bitwise consistent) ----
  f2 h2 = {h, h};
  #pragma unroll
  for (int r = 0; r < 16; ++r) W2T[r] = __builtin_elementwise_fma(SD[r], h2, W2T[r]);
  f2 dh2 = {dh, dh};
  #pragma unroll
  for (int c = 0; c < 16; ++c) W1[c] = __builtin_elementwise_fma(dh2, KC[c], W1[c]);
  b1r += dh;

  // ---- carry ----
  POFb = PB + dh;   // = POFn + b1r_new
  KKF = KKFn;
  dhp = dh;
  tk = tk1;
  tk1 = tk2;
}

__global__ __launch_bounds__(64, 1) void ttt_run(
    const int* __restrict__ seq, const float* __restrict__ enc,
    const float* __restrict__ Gg,
    const float* __restrict__ w1g, const float* __restrict__ b1g,
    const float* __restrict__ w2g, const float* __restrict__ b2g,
    const float* __restrict__ woutg, const float* __restrict__ boutg,
    float* __restrict__ out) {
  __shared__ float enc_s[VOCAB * HD];     // 16 KB
  __shared__ float G_s[VOCAB * VOCAB];    // 16 KB
  __shared__ int   seq_s[SEQLEN];         // 8 KB
  __shared__ float sd_s[64];
  __shared__ float ctx_s[64];
  const int b = blockIdx.x, l = threadIdx.x;
  const int i = l & 31, half = l >> 5;

  #pragma unroll
  for (int q = 0; q < 16; ++q)
    ((float4*)enc_s)[l + 64 * q] = ((const float4*)enc)[l + 64 * q];
  #pragma unroll
  for (int q = 0; q < 16; ++q)
    ((float4*)G_s)[l + 64 * q] = ((const float4*)Gg)[l + 64 * q];
  const int4* seqg = (const int4*)(seq + b * SEQLEN);
  #pragma unroll
  for (int q = 0; q < 8; ++q)
    ((int4*)seq_s)[l + 64 * q] = seqg[l + 64 * q];

  f2 W1[16], W2R2[16], W2T[16];
  {
    float4* w14 = (float4*)&W1[0];
    #pragma unroll
    for (int q = 0; q < 8; ++q) w14[q] = *(const float4*)&w1g[i * 64 + half * 32 + 4 * q];
    float4* w2r4 = (float4*)&W2R2[0];
    #pragma unroll
    for (int q = 0; q < 8; ++q) w2r4[q] = *(const float4*)&w2g[l * 32 + 4 * q];
  }
  #pragma unroll
  for (int r = 0; r < 16; ++r)
    W2T[r] = f2{w2g[(half * 32 + 2 * r) * 32 + i], w2g[(half * 32 + 2 * r + 1) * 32 + i]};
  float b1r = b1g[i];
  float b2r = b2g[l];
  __syncthreads();

  int2 tk  = *(const int2*)&seq_s[0];
  int2 tk1 = *(const int2*)&seq_s[2];
  f2 KA[16], KB[16];
  float vvA, vvB;
  {
    const float* kr = &enc_s[tk.x * HD + half * 32];
    float4* ka4 = (float4*)&KA[0];
    #pragma unroll
    for (int q = 0; q < 8; ++q) ka4[q] = *(const float4*)&kr[4 * q];
    vvA = enc_s[tk.y * HD + l];
  }
  // POFb init: W1 @ k_0 + b1 (first step: dhp=0, KKF=0)
  float POFb, KKF = 0.f, dhp = 0.f;
  {
    f2 p0 = {0.f, 0.f}, p1 = {0.f, 0.f};
    #pragma unroll
    for (int c = 0; c < 16; c += 2) {
      p0 = __builtin_elementwise_fma(W1[c + 0], KA[c + 0], p0);
      p1 = __builtin_elementwise_fma(W1[c + 1], KA[c + 1], p1);
    }
    f2 ps = p0 + p1;
    POFb = xsum32(ps.x + ps.y) + b1r;
  }

  // 511 unrolled pairs (1022 steps) + 1 final step = 1023
  for (int s = 0; s < NSTEPS - 1; s += 2) {
    ttt_step(l, half, enc_s, G_s, seq_s, sd_s, W1, W2R2, W2T, b1r, b2r,
             KA, vvA, KB, vvB, POFb, KKF, dhp, tk, tk1, 2 * s + 4);
    ttt_step(l, half, enc_s, G_s, seq_s, sd_s, W1, W2R2, W2T, b1r, b2r,
             KB, vvB, KA, vvA, POFb, KKF, dhp, tk, tk1, 2 * s + 6);
  }
  ttt_step(l, half, enc_s, G_s, seq_s, sd_s, W1, W2R2, W2T, b1r, b2r,
           KA, vvA, KB, vvB, POFb, KKF, dhp, tk, tk1, 2046 /*result unused*/);

  // ---- tail: ctx = w2f @ relu(w1f @ enc[seq[L-1]] + b1f) + b2f ----
  {
    int tok = seq_s[SEQLEN - 1];
    f2 K[16];
    const float* kr = &enc_s[tok * HD + half * 32];
    float4* k4 = (float4*)&K[0];
    #pragma unroll
    for (int q = 0; q < 8; ++q) k4[q] = *(const float4*)&kr[4 * q];
    f2 a0 = {0.f, 0.f}, a1 = {0.f, 0.f};
    #pragma unroll
    for (int c = 0; c < 16; c += 2) {
      a0 = __builtin_elementwise_fma(W1[c + 0], K[c + 0], a0);
      a1 = __builtin_elementwise_fma(W1[c + 1], K[c + 1], a1);
    }
    f2 as = a0 + a1;
    float pre = xsum32(as.x + as.y) + b1r;
    float h = fmaxf(pre, 0.f);
    f2 shp[16];
    #pragma unroll
    for (int c = 0; c < 16; ++c) {
      float aa = __int_as_float(__builtin_amdgcn_readlane(__float_as_int(h), 2 * c));
      float bb = __int_as_float(__builtin_amdgcn_readlane(__float_as_int(h), 2 * c + 1));
      shp[c] = f2{aa, bb};
    }
    f2 qa = {b2r, 0.f}, qb = {0.f, 0.f}, qc = {0.f, 0.f}, qd = {0.f, 0.f};
    #pragma unroll
    for (int c = 0; c < 16; c += 4) {
      pk_fma_s(qa, W2R2[c + 0], shp[c + 0]);
      pk_fma_s(qb, W2R2[c + 1], shp[c + 1]);
      pk_fma_s(qc, W2R2[c + 2], shp[c + 2]);
      pk_fma_s(qd, W2R2[c + 3], shp[c + 3]);
    }
    ctx_s[l] = ((qa.x + qa.y) + (qb.x + qb.y)) + ((qc.x + qc.y) + (qd.x + qd.y));
    __syncthreads();
    float acc = boutg[l];
    #pragma unroll 8
    for (int jj = 0; jj < 64; ++jj) acc = fmaf(woutg[l * 64 + jj], ctx_s[jj], acc);
    out[b * 64 + l] = acc;
  }
}

extern "C" void kernel_launch(void* const* d_in, const int* in_sizes, int n_in,
                              void* d_out, int out_size, void* d_ws, size_t ws_size,
                              hipStream_t stream) {
  const int*   seq   = (const int*)d_in[0];
  const float* embed = (const float*)d_in[1];
  const float* ffw1  = (const float*)d_in[2];
  const float* ffb1  = (const float*)d_in[3];
  const float* ffw2  = (const float*)d_in[4];
  const float* ffb2  = (const float*)d_in[5];
  const float* ln_g  = (const float*)d_in[6];
  const float* ln_b  = (const float*)d_in[7];
  const float* w1    = (const float*)d_in[8];
  const float* b1    = (const float*)d_in[9];
  const float* w2    = (const float*)d_in[10];
  const float* b2    = (const float*)d_in[11];
  const float* wout  = (const float*)d_in[12];
  const float* bout  = (const float*)d_in[13];
  float* enc = (float*)d_ws;           // 4096 floats
  float* G   = (float*)d_ws + 4096;    // 4096 floats

  enc_build<<<VOCAB, 64, 0, stream>>>(embed, ffw1, ffb1, ffw2, ffb2, ln_g, ln_b, enc);
  gram_build<<<VOCAB, 64, 0, stream>>>(enc, G);
  ttt_run<<<BATCH, 64, 0, stream>>>(seq, enc, G, w1, b1, w2, b2, wout, bout, (float*)d_out);
}

// Round 15
// 379.757 us; speedup vs baseline: 1.1489x; 1.1489x over previous
//
#include <hip/hip_runtime.h>

#define HD 64
#define VOCAB 64
#define BATCH 256
#define SEQLEN 2048
#define NSTEPS ((SEQLEN - 2) / 2)   // 1023
#define LRc 0.05f

typedef __attribute__((ext_vector_type(2))) float f2;

// Cross-half (lane l <-> l^32) sum via v_permlane32_swap_b32 (VALU-class).
// r0+r1 = lo-half + hi-half value in every lane; bit-identical to x + shfl_xor(x,32).
__device__ __forceinline__ float xsum32(float x) {
  unsigned int u = __float_as_uint(x);
  auto r = __builtin_amdgcn_permlane32_swap(u, u, false, false);
  return __uint_as_float(r[0]) + __uint_as_float(r[1]);
}

// ---------------- Kernel 1: build the 64x64 encoder table ----------------
__global__ __launch_bounds__(64, 1) void enc_build(
    const float* __restrict__ embed, const float* __restrict__ ffw1,
    const float* __restrict__ ffb1, const float* __restrict__ ffw2,
    const float* __restrict__ ffb2, const float* __restrict__ ln_g,
    const float* __restrict__ ln_b, float* __restrict__ enc) {
  const int v = blockIdx.x, j = threadIdx.x;
  __shared__ float e_s[HD];
  __shared__ float hid_s[2 * HD];
  float e = embed[v * HD + j];
  e_s[j] = e;
  __syncthreads();
  float ha = ffb1[j], hb = ffb1[HD + j];
  #pragma unroll 8
  for (int h = 0; h < HD; ++h) {
    float eh = e_s[h];
    ha = fmaf(ffw1[j * HD + h], eh, ha);
    hb = fmaf(ffw1[(HD + j) * HD + h], eh, hb);
  }
  hid_s[j] = fmaxf(ha, 0.f);
  hid_s[HD + j] = fmaxf(hb, 0.f);
  __syncthreads();
  float ff = ffb2[j];
  #pragma unroll 8
  for (int h2 = 0; h2 < 2 * HD; ++h2) ff = fmaf(ffw2[j * 2 * HD + h2], hid_s[h2], ff);
  float x = e + ff;
  float mu = x;
  #pragma unroll
  for (int m = 1; m < 64; m <<= 1) mu += __shfl_xor(mu, m, 64);
  mu *= (1.f / 64.f);
  float xc = x - mu;
  float var = xc * xc;
  #pragma unroll
  for (int m = 1; m < 64; m <<= 1) var += __shfl_xor(var, m, 64);
  var *= (1.f / 64.f);
  enc[v * HD + j] = xc / sqrtf(var + 1e-5f) * ln_g[j] + ln_b[j];
}

// ---------------- Kernel 1b: Gram matrix G[u][v] = enc_u . enc_v ----------------
__global__ __launch_bounds__(64, 1) void gram_build(
    const float* __restrict__ enc, float* __restrict__ G) {
  __shared__ float es[VOCAB * HD];
  const int u = blockIdx.x, v = threadIdx.x;
  #pragma unroll
  for (int q = 0; q < 16; ++q)
    ((float4*)es)[v + 64 * q] = ((const float4*)enc)[v + 64 * q];
  __syncthreads();
  const float* a = &es[u * HD];
  const float* bb = &es[v * HD];
  float s0 = 0.f, s1 = 0.f, s2 = 0.f, s3 = 0.f;
  #pragma unroll
  for (int j = 0; j < HD; j += 4) {
    s0 = fmaf(a[j + 0], bb[j + 0], s0);
    s1 = fmaf(a[j + 1], bb[j + 1], s1);
    s2 = fmaf(a[j + 2], bb[j + 2], s2);
    s3 = fmaf(a[j + 3], bb[j + 3], s3);
  }
  G[u * VOCAB + v] = (s0 + s1) + (s2 + s3);
}

// ---------------- Kernel 2: the sequential TTT scan ----------------
// One wave per chain, state in VGPRs. lane l = 32*half + i:
//   W1[c]   = w1[i][32*half + 2c..2c+1]   (f2)
//   W2R2[c] = w2[l][2c..2c+1]             (f2)
//   W2T[r]  = w2[32*half + 2r..2r+1][i]   (f2)
// Carry: pre_{t+1} = POFb + dh_t*G[tok_t][tok_{t+1}],  POFb = W1_t@k_{t+1}+b1.
// h broadcast via LDS h_s -> H2 f2 vector; the ~120cyc round-trip is filled by
// the DEFERRED W1/W2T updates of the previous step (register-only work).
// KX double-buffer: deferred W1 update consumes its old content (k_{t-1})
// before the k_{t+1} prefetch overwrites it.
__device__ __forceinline__ void ttt_step(
    int l, int i, int half,
    const float* __restrict__ enc_s, const float* __restrict__ G_s,
    const int* __restrict__ seq_s, float* __restrict__ sd_s,
    float* __restrict__ h_s,
    f2 (&W1)[16], f2 (&W2R2)[16], f2 (&W2T)[16],
    float& b1r, float& b2r,
    f2 (&KC)[16], float& vvC, f2 (&KX)[16], float& vvN,
    f2 (&SD)[16], float& hp,
    float& POFb, float& KKF, float& dhp,
    int2& tk, int2& tk1, int pidx) {
  // ---- 1. critical head ----
  float pre = fmaf(dhp, KKF, POFb);
  float h = fmaxf(pre, 0.f);

  // ---- 2. h broadcast: LDS write + f2 vector read-back (RT filled below) ----
  h_s[i] = h;  // lanes l and l+32 write identical bits (2-way, free)
  f2 H2[16];
  {
    float4* h4 = (float4*)&H2[0];
    #pragma unroll
    for (int q = 0; q < 8; ++q) h4[q] = *(const float4*)&h_s[4 * q];
  }

  // ---- 3. fillA-1: deferred W1 update (uses KX's OLD content = k_{t-1}) ----
  f2 dhp2 = {dhp, dhp};
  #pragma unroll
  for (int c = 0; c < 16; ++c) W1[c] = __builtin_elementwise_fma(dhp2, KX[c], W1[c]);

  // ---- 4. prefetch k_{t+1} into KX (+ vv, Gram, tokens) ----
  const float* krn = &enc_s[tk1.x * HD + half * 32];
  float4* kx4 = (float4*)&KX[0];
  #pragma unroll
  for (int q = 0; q < 8; ++q) kx4[q] = *(const float4*)&krn[4 * q];
  vvN = enc_s[tk1.y * HD + l];
  float KKFn = G_s[tk.x * VOCAB + tk1.x];
  int2 tk2 = *(const int2*)&seq_s[pidx];

  // ---- 5. fillA-2: deferred W2T update (SD regs = prev step's d, hp = prev h) ----
  f2 hp2 = {hp, hp};
  #pragma unroll
  for (int r = 0; r < 16; ++r) W2T[r] = __builtin_elementwise_fma(SD[r], hp2, W2T[r]);

  // ---- 6. pred[l] = w2[l,:]@h + b2[l]  (pk on H2) ----
  f2 qa = {b2r, 0.f}, qb = {0.f, 0.f}, qc = {0.f, 0.f}, qd = {0.f, 0.f};
  #pragma unroll
  for (int c = 0; c < 16; c += 4) {
    qa = __builtin_elementwise_fma(W2R2[c + 0], H2[c + 0], qa);
    qb = __builtin_elementwise_fma(W2R2[c + 1], H2[c + 1], qb);
    qc = __builtin_elementwise_fma(W2R2[c + 2], H2[c + 2], qc);
    qd = __builtin_elementwise_fma(W2R2[c + 3], H2[c + 3], qd);
  }
  f2 qs = (qa + qb) + (qc + qd);
  float pred = qs.x + qs.y;
  float sR = (vvC - pred) * (2.f * LRc / (float)HD);
  sd_s[l] = sR;  // scaled-d broadcast

  // ---- 7. SD reads issue (consumed after fillB) ----
  {
    const float* drp = &sd_s[half * 32];
    float4* sd4 = (float4*)&SD[0];
    #pragma unroll
    for (int q = 0; q < 8; ++q) sd4[q] = *(const float4*)&drp[4 * q];
  }

  // ---- 8. fillB: W2R update (pk, H2) + POF dot (KX = k_{t+1}, loaded at 4) ----
  f2 sr2 = {sR, sR};
  #pragma unroll
  for (int c = 0; c < 16; ++c) W2R2[c] = __builtin_elementwise_fma(sr2, H2[c], W2R2[c]);
  b2r += sR;
  f2 p0 = {0.f, 0.f}, p1 = {0.f, 0.f};
  #pragma unroll
  for (int c = 0; c < 16; c += 2) {
    p0 = __builtin_elementwise_fma(W1[c + 0], KX[c + 0], p0);
    p1 = __builtin_elementwise_fma(W1[c + 1], KX[c + 1], p1);
  }
  f2 ps = p0 + p1;
  float PB = xsum32(ps.x + ps.y) + b1r;  // b1r pre-update

  // ---- 9. dh' = -LR*(w2^T@d)[i], masked ----
  f2 g0 = {0.f, 0.f}, g1 = {0.f, 0.f};
  #pragma unroll
  for (int r = 0; r < 16; r += 2) {
    g0 = __builtin_elementwise_fma(W2T[r + 0], SD[r + 0], g0);
    g1 = __builtin_elementwise_fma(W2T[r + 1], SD[r + 1], g1);
  }
  f2 gs = g0 + g1;
  float dh = xsum32(gs.x + gs.y);
  dh = (pre > 0.f) ? dh : 0.f;

  // ---- 10. carry (W1/W2T updates deferred into next step's h-window) ----
  b1r += dh;
  POFb = PB + dh;   // = POF + b1r_new
  KKF = KKFn;
  dhp = dh;
  hp = h;
  tk = tk1;
  tk1 = tk2;
}

__global__ __launch_bounds__(64, 1) void ttt_run(
    const int* __restrict__ seq, const float* __restrict__ enc,
    const float* __restrict__ Gg,
    const float* __restrict__ w1g, const float* __restrict__ b1g,
    const float* __restrict__ w2g, const float* __restrict__ b2g,
    const float* __restrict__ woutg, const float* __restrict__ boutg,
    float* __restrict__ out) {
  __shared__ float enc_s[VOCAB * HD];     // 16 KB
  __shared__ float G_s[VOCAB * VOCAB];    // 16 KB
  __shared__ int   seq_s[SEQLEN];         // 8 KB
  __shared__ float sd_s[64];
  __shared__ float h_s[32];
  __shared__ float ctx_s[64];
  const int b = blockIdx.x, l = threadIdx.x;
  const int i = l & 31, half = l >> 5;

  #pragma unroll
  for (int q = 0; q < 16; ++q)
    ((float4*)enc_s)[l + 64 * q] = ((const float4*)enc)[l + 64 * q];
  #pragma unroll
  for (int q = 0; q < 16; ++q)
    ((float4*)G_s)[l + 64 * q] = ((const float4*)Gg)[l + 64 * q];
  const int4* seqg = (const int4*)(seq + b * SEQLEN);
  #pragma unroll
  for (int q = 0; q < 8; ++q)
    ((int4*)seq_s)[l + 64 * q] = seqg[l + 64 * q];

  f2 W1[16], W2R2[16], W2T[16];
  {
    float4* w14 = (float4*)&W1[0];
    #pragma unroll
    for (int q = 0; q < 8; ++q) w14[q] = *(const float4*)&w1g[i * 64 + half * 32 + 4 * q];
    float4* w2r4 = (float4*)&W2R2[0];
    #pragma unroll
    for (int q = 0; q < 8; ++q) w2r4[q] = *(const float4*)&w2g[l * 32 + 4 * q];
  }
  #pragma unroll
  for (int r = 0; r < 16; ++r)
    W2T[r] = f2{w2g[(half * 32 + 2 * r) * 32 + i], w2g[(half * 32 + 2 * r + 1) * 32 + i]};
  float b1r = b1g[i];
  float b2r = b2g[l];
  __syncthreads();

  int2 tk  = *(const int2*)&seq_s[0];
  int2 tk1 = *(const int2*)&seq_s[2];
  f2 KA[16], KB[16], SD[16];
  float vvA, vvB;
  {
    const float* kr = &enc_s[tk.x * HD + half * 32];
    float4* ka4 = (float4*)&KA[0];
    #pragma unroll
    for (int q = 0; q < 8; ++q) ka4[q] = *(const float4*)&kr[4 * q];
    vvA = enc_s[tk.y * HD + l];
  }
  // zero-init deferred-state buffers (avoid 0*garbage = NaN at step 0)
  #pragma unroll
  for (int c = 0; c < 16; ++c) { KB[c] = f2{0.f, 0.f}; SD[c] = f2{0.f, 0.f}; }
  float hp = 0.f;

  // POFb init: W1 @ k_0 + b1 (first step: dhp=0, KKF=0)
  float POFb, KKF = 0.f, dhp = 0.f;
  {
    f2 p0 = {0.f, 0.f}, p1 = {0.f, 0.f};
    #pragma unroll
    for (int c = 0; c < 16; c += 2) {
      p0 = __builtin_elementwise_fma(W1[c + 0], KA[c + 0], p0);
      p1 = __builtin_elementwise_fma(W1[c + 1], KA[c + 1], p1);
    }
    f2 ps = p0 + p1;
    POFb = xsum32(ps.x + ps.y) + b1r;
  }

  // 511 unrolled pairs (1022 steps) + 1 final step = 1023
  for (int s = 0; s < NSTEPS - 1; s += 2) {
    ttt_step(l, i, half, enc_s, G_s, seq_s, sd_s, h_s, W1, W2R2, W2T, b1r, b2r,
             KA, vvA, KB, vvB, SD, hp, POFb, KKF, dhp, tk, tk1, 2 * s + 4);
    ttt_step(l, i, half, enc_s, G_s, seq_s, sd_s, h_s, W1, W2R2, W2T, b1r, b2r,
             KB, vvB, KA, vvA, SD, hp, POFb, KKF, dhp, tk, tk1, 2 * s + 6);
  }
  ttt_step(l, i, half, enc_s, G_s, seq_s, sd_s, h_s, W1, W2R2, W2T, b1r, b2r,
           KA, vvA, KB, vvB, SD, hp, POFb, KKF, dhp, tk, tk1, 2046 /*unused*/);

  // ---- flush the last step's pending W1 update (its KC was KA, untouched) ----
  {
    f2 dhp2 = {dhp, dhp};
    #pragma unroll
    for (int c = 0; c < 16; ++c) W1[c] = __builtin_elementwise_fma(dhp2, KA[c], W1[c]);
  }

  // ---- tail: ctx = w2f @ relu(w1f @ enc[seq[L-1]] + b1f) + b2f ----
  {
    int tok = seq_s[SEQLEN - 1];
    f2 K[16];
    const float* kr = &enc_s[tok * HD + half * 32];
    float4* k4 = (float4*)&K[0];
    #pragma unroll
    for (int q = 0; q < 8; ++q) k4[q] = *(const float4*)&kr[4 * q];
    f2 a0 = {0.f, 0.f}, a1 = {0.f, 0.f};
    #pragma unroll
    for (int c = 0; c < 16; c += 2) {
      a0 = __builtin_elementwise_fma(W1[c + 0], K[c + 0], a0);
      a1 = __builtin_elementwise_fma(W1[c + 1], K[c + 1], a1);
    }
    f2 as = a0 + a1;
    float pre = xsum32(as.x + as.y) + b1r;
    float h = fmaxf(pre, 0.f);
    h_s[i] = h;
    f2 H2[16];
    {
      float4* h4 = (float4*)&H2[0];
      #pragma unroll
      for (int q = 0; q < 8; ++q) h4[q] = *(const float4*)&h_s[4 * q];
    }
    f2 qa = {b2r, 0.f}, qb = {0.f, 0.f}, qc = {0.f, 0.f}, qd = {0.f, 0.f};
    #pragma unroll
    for (int c = 0; c < 16; c += 4) {
      qa = __builtin_elementwise_fma(W2R2[c + 0], H2[c + 0], qa);
      qb = __builtin_elementwise_fma(W2R2[c + 1], H2[c + 1], qb);
      qc = __builtin_elementwise_fma(W2R2[c + 2], H2[c + 2], qc);
      qd = __builtin_elementwise_fma(W2R2[c + 3], H2[c + 3], qd);
    }
    f2 qs = (qa + qb) + (qc + qd);
    ctx_s[l] = qs.x + qs.y;
    __syncthreads();
    float acc = boutg[l];
    #pragma unroll 8
    for (int jj = 0; jj < 64; ++jj) acc = fmaf(woutg[l * 64 + jj], ctx_s[jj], acc);
    out[b * 64 + l] = acc;
  }
}

extern "C" void kernel_launch(void* const* d_in, const int* in_sizes, int n_in,
                              void* d_out, int out_size, void* d_ws, size_t ws_size,
                              hipStream_t stream) {
  const int*   seq   = (const int*)d_in[0];
  const float* embed = (const float*)d_in[1];
  const float* ffw1  = (const float*)d_in[2];
  const float* ffb1  = (const float*)d_in[3];
  const float* ffw2  = (const float*)d_in[4];
  const float* ffb2  = (const float*)d_in[5];
  const float* ln_g  = (const float*)d_in[6];
  const float* ln_b  = (const float*)d_in[7];
  const float* w1    = (const float*)d_in[8];
  const float* b1    = (const float*)d_in[9];
  const float* w2    = (const float*)d_in[10];
  const float* b2    = (const float*)d_in[11];
  const float* wout  = (const float*)d_in[12];
  const float* bout  = (const float*)d_in[13];
  float* enc = (float*)d_ws;           // 4096 floats
  float* G   = (float*)d_ws + 4096;    // 4096 floats

  enc_build<<<VOCAB, 64, 0, stream>>>(embed, ffw1, ffb1, ffw2, ffb2, ln_g, ln_b, enc);
  gram_build<<<VOCAB, 64, 0, stream>>>(enc, G);
  ttt_run<<<BATCH, 64, 0, stream>>>(seq, enc, G, w1, b1, w2, b2, wout, bout, (float*)d_out);
}